// Round 18
// baseline (168.502 us; speedup 1.0000x reference)
//
#include <hip/hip_runtime.h>
#include <hip/hip_bf16.h>

// BaggingMaxPool: out[d] = mean_k( max_{r in indices[k,:]} inp[r][d] )
// N=1024 rows, D=100000 cols, K=20 rounds, SELECT_N=256.
//
// Round-18 restructure: COLUMN-OWNED, ROUND-SEQUENTIAL walk.
// The r9-r17 round-major 16-col tile carried ~63us/CU of DS work (b128
// gather at 64B/entry-wave + a cross-lane reduce per round-instance) and
// every overlap scheme fought to hide ~60us under ~60us. Here:
//  - block owns 128 cols; lane owns 2 cols (bf16x2 in one u32; bf16
//    validated in r16: absmax unchanged). Wave owns rounds 2w,2w+1 and
//    walks their entries SEQUENTIALLY -> acc = 2x float2 = 4 VGPR, NO
//    shfl/DPP/wpart reduce at all. Per entry: 1 ds_read_b32 (256B, 2-way
//    = free) + ~6 VALU.
//  - rows page through LDS: 8 pages x 128 rows bf16 (32KB), double-
//    buffered; per-(round,page) u8 entry lists built once per block,
//    padded to x8 -> branch-free inner loop.
//  - T14 issue-early staging (7 float4/thread = 28 VGPR transient; tiny
//    body keeps total ~60 under the 102 cap), ONE barrier per page,
//    2 blocks/CU (79.6KB LDS), 782 non-persistent blocks for stagger.
// Model: DS ~47us/CU, VALU ~23us, HBM 55-65us -> memory-bound.

#define N_ROWS   1024
#define D_COLS   100000
#define K_ROUNDS 20
#define SEL_N    256
#define NIDX     (K_ROUNDS * SEL_N)     // 5120
#define CPB      128                    // cols per block
#define NCB      ((D_COLS + CPB - 1) / CPB)   // 782
#define PROWS    128                    // rows per page
#define NPAGES   (N_ROWS / PROWS)       // 8
#define ROWU     64                     // u32 per bf16 row (128 cols)
#define BLOCK    640                    // 10 waves
#define WAVES    10
#define LISTCAP  64                     // per-(round,page) entries; mean 32, +6 sigma
#define NEG_INF  (-3.402823466e+38f)

__device__ __forceinline__ unsigned int pk_bf16(float a, float b) {
    union { __hip_bfloat162 h; unsigned int u; } c;
    c.h = __float22bfloat162_rn(make_float2(a, b));
    return c.u;                          // low16 = a (even col), high16 = b (odd col)
}

// 128 rows x 128 cols f32 = 4096 float4 segs; thread t takes segs t, t+640, ...
__device__ __forceinline__ void stage_load(float4 (&pf)[7], const float* __restrict__ inp,
                                           int colbase, int pgbase, int tid) {
    #pragma unroll
    for (int it = 0; it < 7; ++it) {
        const int f = tid + it * BLOCK;
        if (f < PROWS * 32) {
            const int row = f >> 5;
            int cidx = colbase + (f & 31) * 4;
            if (cidx > D_COLS - 4) cidx = D_COLS - 4;   // clamp (tail block)
            pf[it] = *reinterpret_cast<const float4*>(
                inp + (size_t)(pgbase + row) * D_COLS + cidx);
        }
    }
}

__device__ __forceinline__ void stage_write(const float4 (&pf)[7], unsigned int* tb, int tid) {
    #pragma unroll
    for (int it = 0; it < 7; ++it) {
        const int f = tid + it * BLOCK;
        if (f < PROWS * 32) {
            const int row = f >> 5, seg = f & 31;
            uint2 w;
            w.x = pk_bf16(pf[it].x, pf[it].y);
            w.y = pk_bf16(pf[it].z, pf[it].w);
            *reinterpret_cast<uint2*>(tb + row * ROWU + seg * 2) = w;
        }
    }
}

__global__ __launch_bounds__(BLOCK, 5) void bagmax_kernel(
    const float* __restrict__ inp,
    const int*   __restrict__ indices,
    float*       __restrict__ out)
{
    __shared__ unsigned int  tile[2][PROWS * ROWU];             // 2 x 32 KB
    __shared__ unsigned char slist[K_ROUNDS * NPAGES * LISTCAP]; // 10 KB
    __shared__ int           scnt[K_ROUNDS * NPAGES];            // 640 B
    __shared__ float         wpart[WAVES][CPB];                  // 5 KB
    // total 81536 B -> 2 blocks/CU

    const int tid     = threadIdx.x;
    const int lane    = tid & 63;
    const int wave    = tid >> 6;                                // 0..9
    const int colbase = blockIdx.x * CPB;

    // ---- build per-(round,page) entry lists from indices (L2-hot) ----
    if (tid < K_ROUNDS * NPAGES) scnt[tid] = 0;
    __syncthreads();
    for (int i = tid; i < NIDX; i += BLOCK) {
        const int e = indices[i];
        const int L = ((i >> 8) << 3) | (e >> 7);               // round*8 + page
        const int pos = atomicAdd(&scnt[L], 1);
        if (pos < LISTCAP) slist[L * LISTCAP + pos] = (unsigned char)(e & (PROWS - 1));
    }
    __syncthreads();
    if (tid < K_ROUNDS * NPAGES) {                              // pad to x8 (dup entry 0)
        int c = scnt[tid]; if (c > LISTCAP) c = LISTCAP;
        const unsigned char f0 = slist[tid * LISTCAP];
        const int cp = (c + 7) & ~7;
        for (int j = c; j < cp; ++j) slist[tid * LISTCAP + j] = f0;
        scnt[tid] = cp;
    }

    // ---- prologue: stage page 0 ----
    float4 pf[7];
    stage_load(pf, inp, colbase, 0, tid);
    __syncthreads();                      // list build/pad done
    stage_write(pf, &tile[0][0], tid);
    __syncthreads();                      // page 0 visible

    float2 acc0 = make_float2(NEG_INF, NEG_INF);
    float2 acc1 = make_float2(NEG_INF, NEG_INF);
    const int k0 = wave * 2, k1 = wave * 2 + 1;

    #pragma unroll 1
    for (int p = 0; p < NPAGES; ++p) {
        const int cur = p & 1;

        // T14 issue-early: global loads for page p+1 fly under this page's compute
        if (p + 1 < NPAGES) stage_load(pf, inp, colbase, (p + 1) * PROWS, tid);

        const unsigned int* tb = &tile[cur][0];

        #define RND(K, ACC) { \
            const int L = ((K) << 3) | p; \
            const int cnt = scnt[L]; \
            const unsigned char* lp = &slist[L * LISTCAP]; \
            _Pragma("unroll 1") \
            for (int j = 0; j < cnt; j += 8) { \
                const uint2 ch = *reinterpret_cast<const uint2*>(lp + j); \
                const unsigned int cw[2] = {ch.x, ch.y}; \
                _Pragma("unroll") \
                for (int h = 0; h < 2; ++h) { \
                    _Pragma("unroll") \
                    for (int s = 0; s < 32; s += 8) { \
                        const unsigned int e = (cw[h] >> s) & 255u; \
                        const unsigned int v = tb[(e << 6) + lane]; \
                        ACC.x = fmaxf(ACC.x, __uint_as_float(v << 16)); \
                        ACC.y = fmaxf(ACC.y, __uint_as_float(v & 0xFFFF0000u)); \
                    } \
                } \
            } }
        RND(k0, acc0)
        RND(k1, acc1)
        #undef RND

        // write prefetched page into the other buffer (free since last barrier)
        if (p + 1 < NPAGES) stage_write(pf, &tile[cur ^ 1][0], tid);
        __syncthreads();                  // one barrier per page
    }

    // ---- combine: per-lane sum of its 2 round-maxes, cross-wave sum ----
    wpart[wave][lane * 2]     = acc0.x + acc1.x;
    wpart[wave][lane * 2 + 1] = acc0.y + acc1.y;
    __syncthreads();
    if (tid < CPB) {
        const int col = colbase + tid;
        if (col < D_COLS) {
            float s = 0.f;
            #pragma unroll
            for (int w = 0; w < WAVES; ++w) s += wpart[w][tid];
            out[col] = s * (1.0f / (float)K_ROUNDS);
        }
    }
}

extern "C" void kernel_launch(void* const* d_in, const int* in_sizes, int n_in,
                              void* d_out, int out_size, void* d_ws, size_t ws_size,
                              hipStream_t stream) {
    const float* inp     = (const float*)d_in[0];
    const int*   indices = (const int*)d_in[1];
    float*       out     = (float*)d_out;

    bagmax_kernel<<<NCB, BLOCK, 0, stream>>>(inp, indices, out);
}

// Round 20
// 140.990 us; speedup vs baseline: 1.1951x; 1.1951x over previous
//
#include <hip/hip_runtime.h>
#include <hip/hip_fp16.h>

// BaggingMaxPool: out[d] = mean_k( max_{r in indices[k,:]} inp[r][d] )
// N=1024 rows, D=100000 cols, K=20 rounds, SELECT_N=256.
//
// Round-20 = Round-19 with the cvt_pkrtz return-type fix (__fp16 vector).
// Dense streaming select, ALL-VALU (no SALU, no vcc), f16 packed:
//     b   = v_bfe_i32(mask, k, 1)        // 0 or -1, VALU
//     sel = v_bfi_b32(b, v_f16x2, -inf2) // VALU, no vcc
//     acc = v_pk_max_f16(acc, sel)       // VALU, 2 cols at once
// = 3 VALU / round / 2 cols, zero scalar-pipe traffic. Chip VALU ~39us,
// memory ~72us (410MB in + 32MB ws) -> memory-bound with margin.
// f16 RTZ error <= ~0.004 (threshold 0.076; bf16's 0.0156 passed).
// acc[20] u32 = 20 VGPR; A/B 8-row float2 prefetch; ~70 VGPR vs 128 cap.
// Row-split x4 (784 blocks = 3.05 waves/SIMD); partials in ws (16MB);
// masks via tiny kernel into out[0..1023] (overwritten by combine).
// No LDS tile, no hot-loop barriers, no gather.

#define D_COLS  100000
#define NPAIR   50000                   // f16x2 column pairs
#define N_ROWS  1024
#define KR      20
#define NIDX    (KR * 256)              // 5120
#define RS      4                       // row splits
#define RPS     (N_ROWS / RS)           // 256 rows per split
#define BLOCK   256
#define NCB     ((NPAIR + BLOCK - 1) / BLOCK)   // 196
#define NINF2   0xFC00FC00u             // (-inf, -inf) f16x2

typedef __fp16 f16x2_t __attribute__((ext_vector_type(2)));

__device__ __forceinline__ unsigned cvt_pk(float x, float y) {
    union { f16x2_t h; unsigned u; } c;
    c.h = __builtin_amdgcn_cvt_pkrtz(x, y);
    return c.u;
}

// ---- kernel 0: per-row 20-bit round-membership masks -> out[0..1023] ----
__global__ __launch_bounds__(1024) void mask_kernel(
    const int* __restrict__ idx, unsigned* __restrict__ maskbuf)
{
    __shared__ unsigned sm[N_ROWS];
    const int tid = threadIdx.x;        // 1024 threads == N_ROWS
    sm[tid] = 0u;
    __syncthreads();
    for (int i = tid; i < NIDX; i += 1024)
        atomicOr(&sm[idx[i]], 1u << (i >> 8));
    __syncthreads();
    maskbuf[tid] = sm[tid];
}

// ---- kernel 1: dense select-max over this split's 256 rows ----
__device__ __forceinline__ void loadc(float2 (&X)[8], const float* __restrict__ p, int grow0) {
    #pragma unroll
    for (int j = 0; j < 8; ++j)
        X[j] = *reinterpret_cast<const float2*>(p + (size_t)(grow0 + j) * D_COLS);
}

__device__ __forceinline__ void proc8(const float2 (&X)[8], const unsigned* lm, int base,
                                      unsigned ninf, unsigned (&acc)[KR]) {
    #pragma unroll
    for (int j = 0; j < 8; ++j) {
        const unsigned mv = lm[base + j];                 // LDS broadcast -> VGPR
        const unsigned vu = cvt_pk(X[j].x, X[j].y);
        #pragma unroll
        for (int k = 0; k < KR; ++k) {
            const int b = __builtin_amdgcn_sbfe((int)mv, k, 1);   // 0 / -1
            unsigned sel;
            asm("v_bfi_b32 %0, %1, %2, %3" : "=v"(sel) : "v"(b), "v"(vu), "s"(ninf));
            asm("v_pk_max_f16 %0, %0, %1" : "+v"(acc[k]) : "v"(sel));
        }
    }
}

__global__ __launch_bounds__(BLOCK, 4) void select_kernel(
    const float* __restrict__ inp,
    const unsigned* __restrict__ maskbuf,
    unsigned* __restrict__ parts)          // [RS][KR][NPAIR] u32 (f16x2)
{
    __shared__ unsigned lm[RPS];
    const int tid = threadIdx.x;
    const int s   = blockIdx.y;

    lm[tid] = maskbuf[s * RPS + tid];      // BLOCK == RPS == 256
    __syncthreads();

    const int pi  = blockIdx.x * BLOCK + tid;
    const int pic = pi < NPAIR ? pi : NPAIR - 1;        // clamp loads, guard store
    const float* p = inp + (size_t)pic * 2;
    const int r0 = s * RPS;
    const unsigned ninf = NINF2;

    unsigned acc[KR];
    #pragma unroll
    for (int k = 0; k < KR; ++k) acc[k] = NINF2;

    float2 A[8], B[8];
    loadc(A, p, r0);
    #pragma unroll 1
    for (int c = 0; c < RPS; c += 16) {
        loadc(B, p, r0 + c + 8);
        proc8(A, lm, c, ninf, acc);
        const int nb = (c + 16 < RPS) ? (c + 16) : (RPS - 8);   // dead reload on last iter
        loadc(A, p, r0 + nb);
        proc8(B, lm, c + 8, ninf, acc);
    }

    if (pi < NPAIR) {
        #pragma unroll
        for (int k = 0; k < KR; ++k)
            parts[((size_t)(s * KR + k)) * NPAIR + pi] = acc[k];
    }
}

// ---- kernel 2: pk_max across splits, unpack, mean, write f32 ----
__global__ __launch_bounds__(BLOCK) void combine_kernel(
    const unsigned* __restrict__ parts, float* __restrict__ out)
{
    const int pi = blockIdx.x * BLOCK + threadIdx.x;
    if (pi >= NPAIR) return;

    float sx = 0.f, sy = 0.f;
    #pragma unroll
    for (int k = 0; k < KR; ++k) {
        unsigned m = NINF2;
        #pragma unroll
        for (int s = 0; s < RS; ++s) {
            const unsigned v = parts[((size_t)(s * KR + k)) * NPAIR + pi];
            asm("v_pk_max_f16 %0, %0, %1" : "+v"(m) : "v"(v));
        }
        const __half2 h = *reinterpret_cast<const __half2*>(&m);
        const float2 f = __half22float2(h);
        sx += f.x; sy += f.y;
    }
    *reinterpret_cast<float2*>(out + 2 * pi) =
        make_float2(sx * (1.0f / KR), sy * (1.0f / KR));
}

extern "C" void kernel_launch(void* const* d_in, const int* in_sizes, int n_in,
                              void* d_out, int out_size, void* d_ws, size_t ws_size,
                              hipStream_t stream) {
    const float* inp     = (const float*)d_in[0];
    const int*   indices = (const int*)d_in[1];
    float*       out     = (float*)d_out;
    unsigned*    maskbuf = (unsigned*)d_out;   // out[0..1023] as mask scratch;
                                               // combine_kernel overwrites all of out
    unsigned*    parts   = (unsigned*)d_ws;    // RS*KR*NPAIR*4 = 16,000,000 B

    mask_kernel<<<1, 1024, 0, stream>>>(indices, maskbuf);
    dim3 g1(NCB, RS);
    select_kernel<<<g1, BLOCK, 0, stream>>>(inp, maskbuf, parts);
    combine_kernel<<<NCB, BLOCK, 0, stream>>>(parts, out);
}